// Round 6
// baseline (217.733 us; speedup 1.0000x reference)
//
#include <hip/hip_runtime.h>
#include <math.h>

// Problem constants (fixed by the reference setup_inputs)
#define NIMG   64
#define CDIM   64
#define HWPX   4096
#define PARTS  8                 // 8 parts -> 17 MB partials (ws-proven; 16 parts over ws -> atomic fallback!)
#define KCL    128
#define PIXPART (HWPX / PARTS)   // 512 pixels per block
#define TL     32                // pixels per chunk
#define NCHUNK (PIXPART / TL)    // 16
#define SHIFT  10.0f             // softmax shift folded into bias
#define RSQRT128 0.08838834764831845f

// LDS strides in shorts (multiples of 8 so b128 stays 16B-aligned)
#define XP_S 72    // xp planes [32 p][64 c]
#define XC_S 40    // xc planes [64 c][32 p]
#define PH_S 40    // ph planes [128 k][32 p]

typedef __attribute__((ext_vector_type(8))) short short8; // 8 bf16
typedef __attribute__((ext_vector_type(4))) float f32x4;  // MFMA C/D

#define MFMA(a, b, c) __builtin_amdgcn_mfma_f32_16x16x32_bf16((a), (b), (c), 0, 0, 0)

// truncation split: hi = top16 bits, lo = bf16(f - hi). Dropped lo*lo term
// ~2^-16 relative -- well inside the 4.3e-4 output threshold.
__device__ __forceinline__ void tsplit(float f, short& hs, short& ls) {
    unsigned u = __builtin_bit_cast(unsigned, f);
    hs = (short)(u >> 16);
    float hf = __builtin_bit_cast(float, u & 0xffff0000u);
    ls = (short)(__builtin_bit_cast(unsigned, f - hf) >> 16);
}

// ---------------------------------------------------------------------------
// Kernel 1: raw-x planes -> mm1 (W@X) -> in-register softmax -> mm2 (P'@X^T)
// -> per-image last-block finalize (fused; removes the 2nd launch).
// grid = NIMG*PARTS = 512 blocks of 256 threads (round-4-proven shape).
// ---------------------------------------------------------------------------
__global__ __launch_bounds__(256, 2)
void netvlad_main(const float* __restrict__ x,       // [N][C][HW]
                  const float* __restrict__ conv_w,  // [K][C]
                  const float* __restrict__ conv_b,  // [K]
                  const float* __restrict__ cent,    // [K][C]
                  float* __restrict__ vout,          // partials or atomic acc
                  float* __restrict__ asout,
                  int* __restrict__ counters,        // [N], pre-zeroed
                  float* __restrict__ out,           // [N][K*C]
                  int use_atomic)
{
    __shared__ __align__(16) short xp_hi[TL * XP_S],  xp_lo[TL * XP_S];   // 9 KB
    __shared__ __align__(16) short xc_hi[CDIM * XC_S], xc_lo[CDIM * XC_S];// 10 KB
    __shared__ __align__(16) short ph_hi[KCL * PH_S],  ph_lo[KCL * PH_S]; // 20 KB
    __shared__ __align__(16) float redA[TL * 4];      // ssq partials [p][wave]
    __shared__ float sumP[4 * TL];                    // exp-sum partials [wave][p]
    __shared__ int   is_last;

    const int t   = threadIdx.x;
    const int w   = t >> 6;             // wave 0..3
    const int l   = t & 63;
    const int l15 = l & 15, l4 = l >> 4;
    const int n    = blockIdx.x >> 3;
    const int part = blockIdx.x & 7;
    const int p_s  = t & 31;            // staging pixel
    const int sg   = t >> 5;            // staging c-group (8 c's)

    // ---- W fragments in registers (once): A[m=k][kdim=c] ------------------
    short8 wh[2][2], wl[2][2];
    #pragma unroll
    for (int kt = 0; kt < 2; ++kt) {
        const int krow = (2 * w + kt) * 16 + l15;
        #pragma unroll
        for (int ks = 0; ks < 2; ++ks) {
            const float4* wp = (const float4*)(conv_w + krow * CDIM + ks * 32 + l4 * 8);
            float4 wa = wp[0], wb = wp[1];
            float wv[8] = {wa.x, wa.y, wa.z, wa.w, wb.x, wb.y, wb.z, wb.w};
            #pragma unroll
            for (int j = 0; j < 8; ++j) {
                short hs, ls; tsplit(wv[j], hs, ls);
                wh[kt][ks][j] = hs; wl[kt][ks][j] = ls;
            }
        }
    }
    // bias per D-row (k = (2w+kt)*16 + l4*4 + i), pre-shifted
    float cbr[2][4];
    #pragma unroll
    for (int kt = 0; kt < 2; ++kt)
        #pragma unroll
        for (int i = 0; i < 4; ++i)
            cbr[kt][i] = conv_b[(2 * w + kt) * 16 + l4 * 4 + i] - SHIFT;

    f32x4 acc2[2][4];                   // V tiles [kt][ct]
    #pragma unroll
    for (int a = 0; a < 2; ++a)
        #pragma unroll
        for (int b = 0; b < 4; ++b) acc2[a][b] = (f32x4)0.0f;
    float asr[2][4];                    // asum partials per D-row
    #pragma unroll
    for (int a = 0; a < 2; ++a)
        #pragma unroll
        for (int i = 0; i < 4; ++i) asr[a][i] = 0.f;

    const float* xbase = x + (size_t)n * CDIM * HWPX + part * PIXPART;

    // preload chunk 0
    float xv[8];
    #pragma unroll
    for (int j = 0; j < 8; ++j)
        xv[j] = xbase[(sg * 8 + j) * HWPX + p_s];

    for (int ch = 0; ch < NCHUNK; ++ch) {
        // ---- stage: ssq partial + raw-x split planes ----------------------
        float ssq = 0.f;
        #pragma unroll
        for (int j = 0; j < 8; ++j) ssq += xv[j] * xv[j];
        ssq += __shfl_xor(ssq, 32);
        if (l < 32) redA[p_s * 4 + w] = ssq;

        short8 vh, vl;
        #pragma unroll
        for (int j = 0; j < 8; ++j) {
            short hs, ls; tsplit(xv[j], hs, ls);
            vh[j] = hs; vl[j] = ls;
            xc_hi[(sg * 8 + j) * XC_S + p_s] = hs;
            xc_lo[(sg * 8 + j) * XC_S + p_s] = ls;
        }
        *(short8*)&xp_hi[p_s * XP_S + sg * 8] = vh;
        *(short8*)&xp_lo[p_s * XP_S + sg * 8] = vl;
        __syncthreads();                                  // bar: stage done

        // prefetch next chunk while mm1/softmax/mm2 run
        if (ch + 1 < NCHUNK) {
            #pragma unroll
            for (int j = 0; j < 8; ++j)
                xv[j] = xbase[(sg * 8 + j) * HWPX + (ch + 1) * TL + p_s];
        }

        // ---- mm1: a1[kt][pt] = W @ Xraw  (D rows=k, cols=p) --------------
        f32x4 a1[2][2];
        #pragma unroll
        for (int a = 0; a < 2; ++a)
            #pragma unroll
            for (int b = 0; b < 2; ++b) a1[a][b] = (f32x4)0.0f;
        #pragma unroll
        for (int ks = 0; ks < 2; ++ks) {
            #pragma unroll
            for (int pt = 0; pt < 2; ++pt) {
                short8 bh = *(short8*)&xp_hi[(pt * 16 + l15) * XP_S + ks * 32 + l4 * 8];
                short8 bl = *(short8*)&xp_lo[(pt * 16 + l15) * XP_S + ks * 32 + l4 * 8];
                #pragma unroll
                for (int kt = 0; kt < 2; ++kt) {
                    a1[kt][pt] = MFMA(wh[kt][ks], bh, a1[kt][pt]);
                    a1[kt][pt] = MFMA(wh[kt][ks], bl, a1[kt][pt]);
                    a1[kt][pt] = MFMA(wl[kt][ks], bh, a1[kt][pt]);
                }
            }
        }

        // ---- per-column 1/||x||: read 4 ssq partials ----------------------
        float rn[2];
        #pragma unroll
        for (int pt = 0; pt < 2; ++pt) {
            float4 r4 = *(const float4*)&redA[(pt * 16 + l15) * 4];
            rn[pt] = 1.0f / fmaxf(sqrtf((r4.x + r4.y) + (r4.z + r4.w)), 1e-12f);
        }

        // ---- in-register softmax over k (no max pass; bias pre-shifted) ---
        float e[2][2][4], sp[2] = {0.f, 0.f};
        #pragma unroll
        for (int kt = 0; kt < 2; ++kt)
            #pragma unroll
            for (int pt = 0; pt < 2; ++pt)
                #pragma unroll
                for (int i = 0; i < 4; ++i) {
                    float ev = __expf(fmaf(a1[kt][pt][i], rn[pt], cbr[kt][i]));
                    e[kt][pt][i] = ev;
                    sp[pt] += ev;
                }
        #pragma unroll
        for (int pt = 0; pt < 2; ++pt) {
            sp[pt] += __shfl_xor(sp[pt], 16);
            sp[pt] += __shfl_xor(sp[pt], 32);     // wave-sum over its 32 k's
        }
        if (l4 == 0) {
            sumP[w * TL + l15]      = sp[0];
            sumP[w * TL + 16 + l15] = sp[1];
        }
        __syncthreads();                                  // bar: sumP done

        float rden[2], rdn2[2];
        #pragma unroll
        for (int pt = 0; pt < 2; ++pt) {
            const int col = pt * 16 + l15;
            float den = sumP[col] + sumP[TL + col] + sumP[2 * TL + col] + sumP[3 * TL + col];
            rden[pt] = 1.0f / den;
            rdn2[pt] = rden[pt] * rn[pt];          // fold 1/||x|| into P'
        }

        // ---- P' = P * rn, split to planes; asr += P ----------------------
        #pragma unroll
        for (int kt = 0; kt < 2; ++kt)
            #pragma unroll
            for (int i = 0; i < 4; ++i) {
                const int row = (2 * w + kt) * 16 + l4 * 4 + i;
                #pragma unroll
                for (int pt = 0; pt < 2; ++pt) {
                    float ev = e[kt][pt][i];
                    asr[kt][i] = fmaf(ev, rden[pt], asr[kt][i]);
                    float Pn = ev * rdn2[pt];
                    short hs, ls; tsplit(Pn, hs, ls);
                    ph_hi[row * PH_S + pt * 16 + l15] = hs;
                    ph_lo[row * PH_S + pt * 16 + l15] = ls;
                }
            }
        __syncthreads();                                  // bar: P planes done

        // ---- mm2: V[k][c] += P' @ Xraw^T ---------------------------------
        {
            short8 xh2[4], xl2[4];
            #pragma unroll
            for (int ct = 0; ct < 4; ++ct) {
                xh2[ct] = *(short8*)&xc_hi[(ct * 16 + l15) * XC_S + l4 * 8];
                xl2[ct] = *(short8*)&xc_lo[(ct * 16 + l15) * XC_S + l4 * 8];
            }
            #pragma unroll
            for (int kt = 0; kt < 2; ++kt) {
                short8 ah = *(short8*)&ph_hi[((2 * w + kt) * 16 + l15) * PH_S + l4 * 8];
                short8 al = *(short8*)&ph_lo[((2 * w + kt) * 16 + l15) * PH_S + l4 * 8];
                #pragma unroll
                for (int ct = 0; ct < 4; ++ct) {
                    acc2[kt][ct] = MFMA(ah, xh2[ct], acc2[kt][ct]);
                    acc2[kt][ct] = MFMA(ah, xl2[ct], acc2[kt][ct]);
                    acc2[kt][ct] = MFMA(al, xh2[ct], acc2[kt][ct]);
                }
            }
        }
        __syncthreads();                                  // bar: chunk end
    }

    // ---- V write (coalesced: lanes l15 -> consecutive c) ------------------
    float* vg = use_atomic ? vout + (size_t)n * KCL * CDIM
                           : vout + (size_t)(n * PARTS + part) * KCL * CDIM;
    #pragma unroll
    for (int kt = 0; kt < 2; ++kt)
        #pragma unroll
        for (int ct = 0; ct < 4; ++ct)
            #pragma unroll
            for (int i = 0; i < 4; ++i) {
                const int row = (2 * w + kt) * 16 + l4 * 4 + i;
                const int col = ct * 16 + l15;
                if (use_atomic) atomicAdd(&vg[row * CDIM + col], acc2[kt][ct][i]);
                else            vg[row * CDIM + col] = acc2[kt][ct][i];
            }

    // ---- asum: reduce over l15 lanes, lane0-of-16 writes ------------------
    #pragma unroll
    for (int kt = 0; kt < 2; ++kt)
        #pragma unroll
        for (int i = 0; i < 4; ++i) {
            float v = asr[kt][i];
            v += __shfl_xor(v, 1); v += __shfl_xor(v, 2);
            v += __shfl_xor(v, 4); v += __shfl_xor(v, 8);
            if (l15 == 0) {
                const int row = (2 * w + kt) * 16 + l4 * 4 + i;
                if (use_atomic) atomicAdd(&asout[n * KCL + row], v);
                else            asout[(n * PARTS + part) * KCL + row] = v;
            }
        }

    if (use_atomic) return;           // separate finalize kernel handles tail

    // ---- fused finalize: last block of image n sums partials + normalizes -
    __threadfence();                  // release our partial stores (agent)
    if (t == 0)
        is_last = (atomicAdd(&counters[n], 1) == PARTS - 1);
    __syncthreads();
    if (!is_last) return;
    __threadfence();                  // acquire the other 7 blocks' stores

    {
        const int k = t >> 1, c0 = (t & 1) * 32;   // thread -> (k, 32 c's)
        float vsum[32];
        #pragma unroll
        for (int j = 0; j < 32; ++j) vsum[j] = 0.f;
        float av = 0.f;
        for (int pt = 0; pt < PARTS; ++pt) {
            const float* vp = vout + (((size_t)n * PARTS + pt) * KCL + k) * CDIM + c0;
            #pragma unroll
            for (int g = 0; g < 8; ++g) {
                float4 vq = *(const float4*)&vp[4 * g];
                vsum[4 * g + 0] += vq.x; vsum[4 * g + 1] += vq.y;
                vsum[4 * g + 2] += vq.z; vsum[4 * g + 3] += vq.w;
            }
            av += asout[(n * PARTS + pt) * KCL + k];
        }
        const float* cg = cent + k * CDIM + c0;
        float ss = 0.f;
        #pragma unroll
        for (int g = 0; g < 8; ++g) {
            float4 cq = *(const float4*)&cg[4 * g];
            float r0 = vsum[4 * g + 0] - av * cq.x;
            float r1 = vsum[4 * g + 1] - av * cq.y;
            float r2 = vsum[4 * g + 2] - av * cq.z;
            float r3 = vsum[4 * g + 3] - av * cq.w;
            vsum[4 * g + 0] = r0; vsum[4 * g + 1] = r1;
            vsum[4 * g + 2] = r2; vsum[4 * g + 3] = r3;
            ss += r0 * r0 + r1 * r1 + r2 * r2 + r3 * r3;
        }
        ss += __shfl_xor(ss, 1);      // pair (t=2k, 2k+1) completes the row
        // after intra-norm each row is unit -> global denom = sqrt(128)
        const float s = (1.0f / fmaxf(sqrtf(ss), 1e-12f)) * RSQRT128;
        float* og = out + (size_t)n * KCL * CDIM + k * CDIM + c0;
        #pragma unroll
        for (int g = 0; g < 8; ++g) {
            float4 o;
            o.x = vsum[4 * g + 0] * s; o.y = vsum[4 * g + 1] * s;
            o.z = vsum[4 * g + 2] * s; o.w = vsum[4 * g + 3] * s;
            *(float4*)&og[4 * g] = o;
        }
    }
}

// ---------------------------------------------------------------------------
// Fallback finalize (atomic path only): vlad = V - asum*cent; norms.
// ---------------------------------------------------------------------------
__global__ __launch_bounds__(256)
void netvlad_finalize(const float* __restrict__ vacc,    // [N][K][C]
                      const float* __restrict__ asum,    // [N][K]
                      const float* __restrict__ cent,    // [K][C]
                      float* __restrict__ out)           // [N][K*C]
{
    const int t = threadIdx.x;
    const int n  = blockIdx.x >> 3;
    const int kg = blockIdx.x & 7;
    const int k  = kg * 16 + (t >> 4);
    const int c0 = (t & 15) * 4;

    const float* vg = vacc + ((size_t)n * KCL + k) * CDIM + c0;
    float4 a = *(const float4*)vg;
    float vsum[4] = {a.x, a.y, a.z, a.w};
    float av = asum[n * KCL + k];

    float4 cq = *(const float4*)(cent + k * CDIM + c0);
    float cc[4] = {cq.x, cq.y, cq.z, cq.w};
    float ss = 0.f;
    #pragma unroll
    for (int j = 0; j < 4; ++j) {
        vsum[j] -= av * cc[j];
        ss += vsum[j] * vsum[j];
    }
    ss += __shfl_xor(ss, 1); ss += __shfl_xor(ss, 2);
    ss += __shfl_xor(ss, 4); ss += __shfl_xor(ss, 8);
    const float s = (1.0f / fmaxf(sqrtf(ss), 1e-12f)) * RSQRT128;

    float4 o;
    o.x = vsum[0] * s; o.y = vsum[1] * s; o.z = vsum[2] * s; o.w = vsum[3] * s;
    *(float4*)(out + (size_t)n * KCL * CDIM + k * CDIM + c0) = o;
}

// ---------------------------------------------------------------------------
extern "C" void kernel_launch(void* const* d_in, const int* in_sizes, int n_in,
                              void* d_out, int out_size, void* d_ws, size_t ws_size,
                              hipStream_t stream) {
    const float* x     = (const float*)d_in[0];   // [64,64,64,64]
    const float* cent  = (const float*)d_in[1];   // [128,64]
    const float* convw = (const float*)d_in[2];   // [128,64]
    const float* convb = (const float*)d_in[3];   // [128]
    float* out = (float*)d_out;

    const size_t needP = (size_t)NIMG * PARTS * (KCL * CDIM + KCL) * sizeof(float)
                       + NIMG * sizeof(int);
    const int use_atomic = (ws_size >= needP) ? 0 : 1;

    if (!use_atomic) {
        float* vws  = (float*)d_ws;                               // [N][P][K][C]
        float* asws = vws + (size_t)NIMG * PARTS * KCL * CDIM;    // [N][P][K]
        int*   cnt  = (int*)(asws + (size_t)NIMG * PARTS * KCL);  // [N]
        hipMemsetAsync(cnt, 0, NIMG * sizeof(int), stream);
        netvlad_main<<<dim3(NIMG * PARTS), dim3(256), 0, stream>>>(
            x, convw, convb, cent, vws, asws, cnt, out, 0);
    } else {
        float* vws  = (float*)d_ws;                               // [N][K][C]
        float* asws = vws + (size_t)NIMG * KCL * CDIM;            // [N][K]
        const size_t zb = (size_t)NIMG * (KCL * CDIM + KCL) * sizeof(float);
        hipMemsetAsync(d_ws, 0, zb, stream);
        netvlad_main<<<dim3(NIMG * PARTS), dim3(256), 0, stream>>>(
            x, convw, convb, cent, vws, asws, nullptr, out, 1);
        netvlad_finalize<<<dim3(NIMG * 8), dim3(256), 0, stream>>>(
            vws, asws, cent, out);
    }
}

// Round 7
// 134.597 us; speedup vs baseline: 1.6177x; 1.6177x over previous
//
#include <hip/hip_runtime.h>
#include <math.h>

// Problem constants (fixed by the reference setup_inputs)
#define NIMG   64
#define CDIM   64
#define HWPX   4096
#define PARTS  8                 // 8 parts -> 17 MB partials fits ws (16 doesn't!)
#define KCL    128
#define PIXPART (HWPX / PARTS)   // 512 pixels per block
#define TL     32                // pixels per chunk
#define NCHUNK (PIXPART / TL)    // 16
#define SHIFT  10.0f             // softmax shift folded into bias
#define RSQRT128 0.08838834764831845f

// LDS strides in shorts (multiples of 8 so b128 stays 16B-aligned)
#define XP_S 72    // xp planes [32 p][64 c]
#define XC_S 40    // xc planes [64 c][32 p]
#define PH_S 40    // ph planes [128 k][32 p]

typedef __attribute__((ext_vector_type(8))) short short8; // 8 bf16
typedef __attribute__((ext_vector_type(4))) float f32x4;  // MFMA C/D

#define MFMA(a, b, c) __builtin_amdgcn_mfma_f32_16x16x32_bf16((a), (b), (c), 0, 0, 0)

// truncation split: hi = top16 bits, lo = bf16(f - hi). Dropped lo*lo term
// ~2^-16 relative -- well inside the 4.3e-4 output threshold.
__device__ __forceinline__ void tsplit(float f, short& hs, short& ls) {
    unsigned u = __builtin_bit_cast(unsigned, f);
    hs = (short)(u >> 16);
    float hf = __builtin_bit_cast(float, u & 0xffff0000u);
    ls = (short)(__builtin_bit_cast(unsigned, f - hf) >> 16);
}

// ---------------------------------------------------------------------------
// Kernel 1: raw-x planes -> mm1 (W@X) -> in-register softmax -> mm2 (P'@X^T)
// grid = NIMG*PARTS = 512 blocks of 256 threads (round-4-proven shape).
// 3 barriers/chunk: the P-store -> mm2 barrier is removed because wave w
// writes and reads only its own 32 ph rows (intra-wave LDS transpose;
// per-wave DS ordering makes it safe). NO device-scope fences in this
// kernel -- fused finalize with __threadfence cost 3x (round 6).
// ---------------------------------------------------------------------------
__global__ __launch_bounds__(256, 2)
void netvlad_main(const float* __restrict__ x,       // [N][C][HW]
                  const float* __restrict__ conv_w,  // [K][C]
                  const float* __restrict__ conv_b,  // [K]
                  float* __restrict__ vout,          // partials or atomic acc
                  float* __restrict__ asout,
                  int use_atomic)
{
    __shared__ __align__(16) short xp_hi[TL * XP_S],  xp_lo[TL * XP_S];   // 9 KB
    __shared__ __align__(16) short xc_hi[CDIM * XC_S], xc_lo[CDIM * XC_S];// 10 KB
    __shared__ __align__(16) short ph_hi[KCL * PH_S],  ph_lo[KCL * PH_S]; // 20 KB
    __shared__ float redA[4 * 33];    // ssq partials [wave][p], stride 33
    __shared__ float sumP[4 * TL];    // exp-sum partials [wave][p]

    const int t   = threadIdx.x;
    const int w   = t >> 6;             // wave 0..3
    const int l   = t & 63;
    const int l15 = l & 15, l4 = l >> 4;
    const int n    = blockIdx.x >> 3;
    const int part = blockIdx.x & 7;
    const int p_s  = t & 31;            // staging pixel
    const int sg   = t >> 5;            // staging c-group (8 c's)

    // ---- W fragments in registers (once): A[m=k][kdim=c] ------------------
    short8 wh[2][2], wl[2][2];
    #pragma unroll
    for (int kt = 0; kt < 2; ++kt) {
        const int krow = (2 * w + kt) * 16 + l15;
        #pragma unroll
        for (int ks = 0; ks < 2; ++ks) {
            const float4* wp = (const float4*)(conv_w + krow * CDIM + ks * 32 + l4 * 8);
            float4 wa = wp[0], wb = wp[1];
            float wv[8] = {wa.x, wa.y, wa.z, wa.w, wb.x, wb.y, wb.z, wb.w};
            #pragma unroll
            for (int j = 0; j < 8; ++j) {
                short hs, ls; tsplit(wv[j], hs, ls);
                wh[kt][ks][j] = hs; wl[kt][ks][j] = ls;
            }
        }
    }
    // bias per D-row (k = (2w+kt)*16 + l4*4 + i), pre-shifted
    float cbr[2][4];
    #pragma unroll
    for (int kt = 0; kt < 2; ++kt)
        #pragma unroll
        for (int i = 0; i < 4; ++i)
            cbr[kt][i] = conv_b[(2 * w + kt) * 16 + l4 * 4 + i] - SHIFT;

    f32x4 acc2[2][4];                   // V tiles [kt][ct]
    #pragma unroll
    for (int a = 0; a < 2; ++a)
        #pragma unroll
        for (int b = 0; b < 4; ++b) acc2[a][b] = (f32x4)0.0f;
    float asr[2][4];                    // asum partials per D-row
    #pragma unroll
    for (int a = 0; a < 2; ++a)
        #pragma unroll
        for (int i = 0; i < 4; ++i) asr[a][i] = 0.f;

    const float* xbase = x + (size_t)n * CDIM * HWPX + part * PIXPART;

    // preload chunk 0
    float xv[8];
    #pragma unroll
    for (int j = 0; j < 8; ++j)
        xv[j] = xbase[(sg * 8 + j) * HWPX + p_s];

    for (int ch = 0; ch < NCHUNK; ++ch) {
        // ---- stage: ssq partial + raw-x split planes ----------------------
        float ssq = 0.f;
        #pragma unroll
        for (int j = 0; j < 8; ++j) ssq += xv[j] * xv[j];
        ssq += __shfl_xor(ssq, 32);              // combine the wave's 2 sg's
        if (l < 32) redA[w * 33 + p_s] = ssq;

        short8 vh, vl;
        #pragma unroll
        for (int j = 0; j < 8; ++j) {
            short hs, ls; tsplit(xv[j], hs, ls);
            vh[j] = hs; vl[j] = ls;
            xc_hi[(sg * 8 + j) * XC_S + p_s] = hs;
            xc_lo[(sg * 8 + j) * XC_S + p_s] = ls;
        }
        *(short8*)&xp_hi[p_s * XP_S + sg * 8] = vh;
        *(short8*)&xp_lo[p_s * XP_S + sg * 8] = vl;
        __syncthreads();                                  // bar 1: stage done

        // prefetch next chunk while mm1/softmax/mm2 run
        if (ch + 1 < NCHUNK) {
            #pragma unroll
            for (int j = 0; j < 8; ++j)
                xv[j] = xbase[(sg * 8 + j) * HWPX + (ch + 1) * TL + p_s];
        }

        // ---- mm1: a1[kt][pt] = W @ Xraw  (D rows=k, cols=p) --------------
        f32x4 a1[2][2];
        #pragma unroll
        for (int a = 0; a < 2; ++a)
            #pragma unroll
            for (int b = 0; b < 2; ++b) a1[a][b] = (f32x4)0.0f;
        #pragma unroll
        for (int ks = 0; ks < 2; ++ks) {
            #pragma unroll
            for (int pt = 0; pt < 2; ++pt) {
                short8 bh = *(short8*)&xp_hi[(pt * 16 + l15) * XP_S + ks * 32 + l4 * 8];
                short8 bl = *(short8*)&xp_lo[(pt * 16 + l15) * XP_S + ks * 32 + l4 * 8];
                #pragma unroll
                for (int kt = 0; kt < 2; ++kt) {
                    a1[kt][pt] = MFMA(wh[kt][ks], bh, a1[kt][pt]);
                    a1[kt][pt] = MFMA(wh[kt][ks], bl, a1[kt][pt]);
                    a1[kt][pt] = MFMA(wl[kt][ks], bh, a1[kt][pt]);
                }
            }
        }

        // ---- per-column 1/||x||: sum the 4 per-wave ssq partials ----------
        float rn[2];
        #pragma unroll
        for (int pt = 0; pt < 2; ++pt) {
            const int col = pt * 16 + l15;
            float s0 = redA[col] + redA[33 + col];
            float s1 = redA[2 * 33 + col] + redA[3 * 33 + col];
            rn[pt] = 1.0f / fmaxf(sqrtf(s0 + s1), 1e-12f);
        }

        // ---- in-register softmax over k (no max pass; bias pre-shifted) ---
        float e[2][2][4], sp[2] = {0.f, 0.f};
        #pragma unroll
        for (int kt = 0; kt < 2; ++kt)
            #pragma unroll
            for (int pt = 0; pt < 2; ++pt)
                #pragma unroll
                for (int i = 0; i < 4; ++i) {
                    float ev = __expf(fmaf(a1[kt][pt][i], rn[pt], cbr[kt][i]));
                    e[kt][pt][i] = ev;
                    sp[pt] += ev;
                }
        #pragma unroll
        for (int pt = 0; pt < 2; ++pt) {
            sp[pt] += __shfl_xor(sp[pt], 16);
            sp[pt] += __shfl_xor(sp[pt], 32);     // wave-sum over its 32 k's
        }
        if (l4 == 0) {
            sumP[w * TL + l15]      = sp[0];
            sumP[w * TL + 16 + l15] = sp[1];
        }
        __syncthreads();                                  // bar 2: sumP done

        float rden[2], rdn2[2];
        #pragma unroll
        for (int pt = 0; pt < 2; ++pt) {
            const int col = pt * 16 + l15;
            float den = sumP[col] + sumP[TL + col] + sumP[2 * TL + col] + sumP[3 * TL + col];
            rden[pt] = 1.0f / den;
            rdn2[pt] = rden[pt] * rn[pt];          // fold 1/||x|| into P'
        }

        // ---- P' = P * rn, split to planes (wave's own 32 ph rows) ---------
        #pragma unroll
        for (int kt = 0; kt < 2; ++kt)
            #pragma unroll
            for (int i = 0; i < 4; ++i) {
                const int row = (2 * w + kt) * 16 + l4 * 4 + i;
                #pragma unroll
                for (int pt = 0; pt < 2; ++pt) {
                    float ev = e[kt][pt][i];
                    asr[kt][i] = fmaf(ev, rden[pt], asr[kt][i]);
                    float Pn = ev * rdn2[pt];
                    short hs, ls; tsplit(Pn, hs, ls);
                    ph_hi[row * PH_S + pt * 16 + l15] = hs;
                    ph_lo[row * PH_S + pt * 16 + l15] = ls;
                }
            }
        // NO barrier here: mm2 reads only the ph rows this wave just wrote
        // (intra-wave LDS ordering is guaranteed), and xc was stage-staged
        // behind bar 1.

        // ---- mm2: V[k][c] += P' @ Xraw^T ---------------------------------
        {
            short8 xh2[4], xl2[4];
            #pragma unroll
            for (int ct = 0; ct < 4; ++ct) {
                xh2[ct] = *(short8*)&xc_hi[(ct * 16 + l15) * XC_S + l4 * 8];
                xl2[ct] = *(short8*)&xc_lo[(ct * 16 + l15) * XC_S + l4 * 8];
            }
            #pragma unroll
            for (int kt = 0; kt < 2; ++kt) {
                short8 ah = *(short8*)&ph_hi[((2 * w + kt) * 16 + l15) * PH_S + l4 * 8];
                short8 al = *(short8*)&ph_lo[((2 * w + kt) * 16 + l15) * PH_S + l4 * 8];
                #pragma unroll
                for (int ct = 0; ct < 4; ++ct) {
                    acc2[kt][ct] = MFMA(ah, xh2[ct], acc2[kt][ct]);
                    acc2[kt][ct] = MFMA(ah, xl2[ct], acc2[kt][ct]);
                    acc2[kt][ct] = MFMA(al, xh2[ct], acc2[kt][ct]);
                }
            }
        }
        __syncthreads();                                  // bar 3: chunk end
    }

    // ---- V write (coalesced: lanes l15 -> consecutive c) ------------------
    float* vg = use_atomic ? vout + (size_t)n * KCL * CDIM
                           : vout + (size_t)(n * PARTS + part) * KCL * CDIM;
    #pragma unroll
    for (int kt = 0; kt < 2; ++kt)
        #pragma unroll
        for (int ct = 0; ct < 4; ++ct)
            #pragma unroll
            for (int i = 0; i < 4; ++i) {
                const int row = (2 * w + kt) * 16 + l4 * 4 + i;
                const int col = ct * 16 + l15;
                if (use_atomic) atomicAdd(&vg[row * CDIM + col], acc2[kt][ct][i]);
                else            vg[row * CDIM + col] = acc2[kt][ct][i];
            }

    // ---- asum: reduce over l15 lanes, lane0-of-16 writes ------------------
    #pragma unroll
    for (int kt = 0; kt < 2; ++kt)
        #pragma unroll
        for (int i = 0; i < 4; ++i) {
            float v = asr[kt][i];
            v += __shfl_xor(v, 1); v += __shfl_xor(v, 2);
            v += __shfl_xor(v, 4); v += __shfl_xor(v, 8);
            if (l15 == 0) {
                const int row = (2 * w + kt) * 16 + l4 * 4 + i;
                if (use_atomic) atomicAdd(&asout[n * KCL + row], v);
                else            asout[(n * PARTS + part) * KCL + row] = v;
            }
        }
}

// ---------------------------------------------------------------------------
// Kernel 2: sum partials; vlad = V - asum*cent; intra-norm; global norm.
// After intra-norm every row has unit L2 norm -> global denom = sqrt(128).
// grid = NIMG*8 blocks x 256 threads; thread -> (k, 4 c's). Fully parallel.
// ---------------------------------------------------------------------------
__global__ __launch_bounds__(256)
void netvlad_finalize(const float* __restrict__ vpart,   // [N][nparts][K][C]
                      const float* __restrict__ aspart,  // [N][nparts][K]
                      const float* __restrict__ cent,    // [K][C]
                      float* __restrict__ out,           // [N][K*C]
                      int nparts)
{
    const int t = threadIdx.x;
    const int n  = blockIdx.x >> 3;
    const int kg = blockIdx.x & 7;
    const int k  = kg * 16 + (t >> 4);
    const int c0 = (t & 15) * 4;

    float vsum[4] = {0.f, 0.f, 0.f, 0.f};
    float av = 0.f;
    for (int pt = 0; pt < nparts; ++pt) {
        const float* vg = vpart + (((size_t)n * nparts + pt) * KCL + k) * CDIM + c0;
        float4 a = *(const float4*)vg;
        vsum[0] += a.x; vsum[1] += a.y; vsum[2] += a.z; vsum[3] += a.w;
        av += aspart[(n * nparts + pt) * KCL + k];
    }

    float4 cq = *(const float4*)(cent + k * CDIM + c0);
    float cc[4] = {cq.x, cq.y, cq.z, cq.w};
    float ss = 0.f;
    #pragma unroll
    for (int j = 0; j < 4; ++j) {
        vsum[j] -= av * cc[j];
        ss += vsum[j] * vsum[j];
    }
    // row sumsq over the 16 lanes covering this k
    ss += __shfl_xor(ss, 1); ss += __shfl_xor(ss, 2);
    ss += __shfl_xor(ss, 4); ss += __shfl_xor(ss, 8);
    const float s = (1.0f / fmaxf(sqrtf(ss), 1e-12f)) * RSQRT128;

    float4 o;
    o.x = vsum[0] * s; o.y = vsum[1] * s; o.z = vsum[2] * s; o.w = vsum[3] * s;
    *(float4*)(out + (size_t)n * KCL * CDIM + k * CDIM + c0) = o;
}

// ---------------------------------------------------------------------------
extern "C" void kernel_launch(void* const* d_in, const int* in_sizes, int n_in,
                              void* d_out, int out_size, void* d_ws, size_t ws_size,
                              hipStream_t stream) {
    const float* x     = (const float*)d_in[0];   // [64,64,64,64]
    const float* cent  = (const float*)d_in[1];   // [128,64]
    const float* convw = (const float*)d_in[2];   // [128,64]
    const float* convb = (const float*)d_in[3];   // [128]
    float* out = (float*)d_out;

    const size_t needP = (size_t)NIMG * PARTS * (KCL * CDIM + KCL) * sizeof(float);
    int nparts, use_atomic;
    if (ws_size >= needP) { nparts = PARTS; use_atomic = 0; }
    else                  { nparts = 1;     use_atomic = 1; }

    float* vws  = (float*)d_ws;                               // [N][nparts][K][C]
    float* asws = vws + (size_t)NIMG * nparts * KCL * CDIM;   // [N][nparts][K]
    if (use_atomic) {
        const size_t zb = (size_t)NIMG * (KCL * CDIM + KCL) * sizeof(float);
        hipMemsetAsync(d_ws, 0, zb, stream);
    }

    netvlad_main<<<dim3(NIMG * PARTS), dim3(256), 0, stream>>>(x, convw, convb, vws, asws, use_atomic);
    netvlad_finalize<<<dim3(NIMG * 8), dim3(256), 0, stream>>>(vws, asws, cent, out, nparts);
}